// Round 4
// baseline (376.033 us; speedup 1.0000x reference)
//
#include <hip/hip_runtime.h>
#include <math.h>

#define N_NODES 100000
#define N_EDGES 800000
#define NEG_SLOPE 0.2f

typedef __attribute__((ext_vector_type(8))) short short8;
typedef __attribute__((ext_vector_type(4))) float floatx4;

__device__ __forceinline__ float lrelu(float x) { return x > 0.f ? x : NEG_SLOPE * x; }

__device__ __forceinline__ unsigned bf16_rne(float f) {
    unsigned u = __float_as_uint(f);
    return (u + 0x7fffu + ((u >> 16) & 1u)) >> 16;
}
__device__ __forceinline__ unsigned bfpack(float lo, float hi) {
    return bf16_rne(lo) | (bf16_rne(hi) << 16);
}
__device__ __forceinline__ float bflo(unsigned p) { return __uint_as_float(p << 16); }
__device__ __forceinline__ float bfhi(unsigned p) { return __uint_as_float(p & 0xffff0000u); }

// ---------------- CSR build ----------------
__global__ void k_hist(const int* __restrict__ dst, int* __restrict__ deg) {
    int e = blockIdx.x * blockDim.x + threadIdx.x;
    if (e < N_EDGES) atomicAdd(&deg[dst[e]], 1);
}

__global__ __launch_bounds__(256) void k_scan1(const int* __restrict__ deg,
                                               int* __restrict__ rs,
                                               int* __restrict__ bsums) {
    __shared__ int sd[256];
    int tid = threadIdx.x;
    int base = blockIdx.x * 1024 + tid * 4;
    int v0 = (base + 0 < N_NODES) ? deg[base + 0] : 0;
    int v1 = (base + 1 < N_NODES) ? deg[base + 1] : 0;
    int v2 = (base + 2 < N_NODES) ? deg[base + 2] : 0;
    int v3 = (base + 3 < N_NODES) ? deg[base + 3] : 0;
    int t = v0 + v1 + v2 + v3;
    sd[tid] = t;
    __syncthreads();
    int incl = t;
    for (int off = 1; off < 256; off <<= 1) {
        int x = (tid >= off) ? sd[tid - off] : 0;
        __syncthreads();
        incl += x;
        sd[tid] = incl;
        __syncthreads();
    }
    int excl = incl - t;
    if (base + 0 < N_NODES) rs[base + 0] = excl;
    if (base + 1 < N_NODES) rs[base + 1] = excl + v0;
    if (base + 2 < N_NODES) rs[base + 2] = excl + v0 + v1;
    if (base + 3 < N_NODES) rs[base + 3] = excl + v0 + v1 + v2;
    if (tid == 255) bsums[blockIdx.x] = incl;
}

__global__ __launch_bounds__(256) void k_scan2(int* __restrict__ bs, int nb) {
    __shared__ int sd[256];
    int tid = threadIdx.x;
    int t = (tid < nb) ? bs[tid] : 0;
    sd[tid] = t;
    __syncthreads();
    int incl = t;
    for (int off = 1; off < 256; off <<= 1) {
        int x = (tid >= off) ? sd[tid - off] : 0;
        __syncthreads();
        incl += x;
        sd[tid] = incl;
        __syncthreads();
    }
    if (tid < nb) bs[tid] = incl - t;
}

__global__ void k_scan3(int* __restrict__ rs, const int* __restrict__ bs,
                        int* __restrict__ cursor) {
    int idx = blockIdx.x * blockDim.x + threadIdx.x;
    if (idx < N_NODES) {
        int v = rs[idx] + bs[idx >> 10];
        rs[idx] = v;
        cursor[idx] = v;
    }
}

__global__ void k_scatter(const int* __restrict__ src, const int* __restrict__ dst,
                          int* __restrict__ cursor, int* __restrict__ csr_src,
                          int* __restrict__ csr_dst) {
    int e = blockIdx.x * blockDim.x + threadIdx.x;
    if (e < N_EDGES) {
        int d = dst[e];
        int p = atomicAdd(&cursor[d], 1);
        csr_src[p] = src[e];
        csr_dst[p] = d;
    }
}

// ---------------- W transpose + bf16 convert for both layers ----------------
__global__ __launch_bounds__(256) void k_wprep2(const float* __restrict__ W1,
                                                const float* __restrict__ W2,
                                                unsigned short* __restrict__ wt1,
                                                unsigned short* __restrict__ wt2) {
    int tid = blockIdx.x * 256 + threadIdx.x;   // 0..32767
    const float* W = (tid < 16384) ? W1 : W2;
    unsigned short* wt = (tid < 16384) ? wt1 : wt2;
    int t = tid & 16383;
    int n = t >> 7, k = t & 127;
    wt[t] = (unsigned short)bf16_rne(W[k * 128 + n]);
}

// ---------------- MFMA GEMM: h = X @ W (bf16 in, fp32 acc) + el/er epilogue ----------------
__global__ __launch_bounds__(256) void k_gemm(const void* __restrict__ Xv,
                                              const unsigned short* __restrict__ wt,
                                              const float* __restrict__ al,
                                              const float* __restrict__ ar,
                                              unsigned* __restrict__ Hb,
                                              float* __restrict__ EL,
                                              float* __restrict__ ER,
                                              int src_bf16) {
    __shared__ unsigned short wsh[128 * 128];   // 32 KB, swizzled [n][k] bf16
    int tid = threadIdx.x;
    int w = tid >> 6, lane = tid & 63;
    int q = lane >> 4, nl = lane & 15;
    int base = blockIdx.x * 128;

    const uint4* wt4 = (const uint4*)wt;
    #pragma unroll
    for (int i = 0; i < 8; i++) {
        int idx = tid + i * 256;                // 0..2047 chunks of 8 shorts
        int rn = idx >> 4, c8 = idx & 15;
        int kc = c8 >> 2, qq = c8 & 3;
        int slot = rn * 128 + ((kc ^ ((rn >> 2) & 3)) * 4 + (qq ^ (rn & 3))) * 8;
        *(uint4*)&wsh[slot] = wt4[idx];
    }

    short8 afr[2][4];
    int row0 = base + w * 32 + nl;
    if (!src_bf16) {
        const float4* X4 = (const float4*)Xv;
        #pragma unroll
        for (int rt = 0; rt < 2; rt++) {
            int rr = row0 + rt * 16; if (rr > N_NODES - 1) rr = N_NODES - 1;
            const float4* px = X4 + (size_t)rr * 32 + q * 2;
            #pragma unroll
            for (int kc = 0; kc < 4; kc++) {
                float4 u = px[kc * 8], v = px[kc * 8 + 1];
                short8 f;
                f[0] = (short)bf16_rne(u.x); f[1] = (short)bf16_rne(u.y);
                f[2] = (short)bf16_rne(u.z); f[3] = (short)bf16_rne(u.w);
                f[4] = (short)bf16_rne(v.x); f[5] = (short)bf16_rne(v.y);
                f[6] = (short)bf16_rne(v.z); f[7] = (short)bf16_rne(v.w);
                afr[rt][kc] = f;
            }
        }
    } else {
        const unsigned short* Xb = (const unsigned short*)Xv;
        #pragma unroll
        for (int rt = 0; rt < 2; rt++) {
            int rr = row0 + rt * 16; if (rr > N_NODES - 1) rr = N_NODES - 1;
            #pragma unroll
            for (int kc = 0; kc < 4; kc++)
                afr[rt][kc] = *(const short8*)(Xb + (size_t)rr * 128 + kc * 32 + q * 8);
        }
    }

    floatx4 acc[2][8];
    #pragma unroll
    for (int rt = 0; rt < 2; rt++)
        #pragma unroll
        for (int ct = 0; ct < 8; ct++)
            acc[rt][ct] = (floatx4){0.f, 0.f, 0.f, 0.f};

    __syncthreads();

    int sw_hi = (nl >> 2) & 3, sw_lo = nl & 3;
    #pragma unroll
    for (int ct = 0; ct < 8; ct++) {
        int rbase = (ct * 16 + nl) * 128;
        #pragma unroll
        for (int kc = 0; kc < 4; kc++) {
            short8 b = *(const short8*)&wsh[rbase + ((kc ^ sw_hi) * 4 + (q ^ sw_lo)) * 8];
            acc[0][ct] = __builtin_amdgcn_mfma_f32_16x16x32_bf16(afr[0][kc], b, acc[0][ct], 0, 0, 0);
            acc[1][ct] = __builtin_amdgcn_mfma_f32_16x16x32_bf16(afr[1][kc], b, acc[1][ct], 0, 0, 0);
        }
    }

    float all_[4], alh_[4], arl_[4], arh_[4];
    #pragma unroll
    for (int h = 0; h < 4; h++) {
        all_[h] = al[h * 32 + nl]; alh_[h] = al[h * 32 + 16 + nl];
        arl_[h] = ar[h * 32 + nl]; arh_[h] = ar[h * 32 + 16 + nl];
    }
    #pragma unroll
    for (int rt = 0; rt < 2; rt++) {
        #pragma unroll
        for (int r = 0; r < 4; r++) {
            int row = base + w * 32 + rt * 16 + q * 4 + r;
            bool valid = row < N_NODES;
            unsigned* hrow = Hb + (size_t)row * 64;
            #pragma unroll
            for (int ct = 0; ct < 8; ct++) {
                float vlo = acc[rt][ct][r];
                float vhi = __shfl_down(vlo, 1);
                if (valid && !(nl & 1)) hrow[ct * 8 + (nl >> 1)] = bfpack(vlo, vhi);
            }
            #pragma unroll
            for (int h = 0; h < 4; h++) {
                float pel = acc[rt][2 * h][r] * all_[h] + acc[rt][2 * h + 1][r] * alh_[h];
                float per = acc[rt][2 * h][r] * arl_[h] + acc[rt][2 * h + 1][r] * arh_[h];
                #pragma unroll
                for (int o = 1; o < 16; o <<= 1) {
                    pel += __shfl_xor(pel, o);
                    per += __shfl_xor(per, o);
                }
                if (valid && nl == 0) { EL[row * 4 + h] = pel; ER[row * 4 + h] = per; }
            }
        }
    }
}

// ---------------- alpha: edge-parallel unnormalized attention weights ----------------
__global__ __launch_bounds__(256) void k_alpha(const int* __restrict__ csr_src,
                                               const int* __restrict__ csr_dst,
                                               const float* __restrict__ EL,
                                               const float* __restrict__ ER,
                                               float* __restrict__ alpha) {
    int p = blockIdx.x * 256 + threadIdx.x;
    if (p >= N_EDGES) return;
    int s = csr_src[p], d = csr_dst[p];
    float4 el4 = ((const float4*)EL)[s];
    float4 er4 = ((const float4*)ER)[d];
    float4 a;
    a.x = __expf(lrelu(el4.x + er4.x));
    a.y = __expf(lrelu(el4.y + er4.y));
    a.z = __expf(lrelu(el4.z + er4.z));
    a.w = __expf(lrelu(el4.w + er4.w));
    ((float4*)alpha)[p] = a;
}

// ---------------- gather v2: one wave per node, half-wave = 2 edges per iter ----------------
// lane = half*32 + l; lane covers output cols 4l..4l+3; half 0/1 takes even/odd edges.
// Denominator: every lane of head h reads the same alpha stream -> per-lane sum, no reduce.
__global__ __launch_bounds__(256) void k_gather(const int* __restrict__ rs,
                                                const int* __restrict__ deg,
                                                const int* __restrict__ csr_src,
                                                const float* __restrict__ alpha,
                                                const unsigned* __restrict__ Hb,
                                                const float* __restrict__ bias,
                                                void* __restrict__ out,
                                                int final_layer) {
    int wid = (blockIdx.x * blockDim.x + threadIdx.x) >> 6;
    if (wid >= N_NODES) return;
    int lane = threadIdx.x & 63;
    int half = lane >> 5, l = lane & 31;
    int hh = l >> 3;
    int n = wid;
    int start = rs[n], d = deg[n], end = start + d;

    float a0 = 0.f, a1 = 0.f, a2 = 0.f, a3 = 0.f, sa = 0.f;
    if (d > 0) {
        int idx = start + half;
        int ic = (idx >= end) ? end - 1 : idx;
        int se = csr_src[ic];
        float wv = alpha[ic * 4 + hh];
        for (int j = start; j < end; j += 2) {
            int se_c = se;
            float w_c = (j + half < end) ? wv : 0.f;
            int jn = j + 2;
            if (jn < end) {
                int i2 = jn + half;
                int ic2 = (i2 >= end) ? end - 1 : i2;
                se = csr_src[ic2];
                wv = alpha[ic2 * 4 + hh];
            }
            uint2 p = *(const uint2*)(Hb + (size_t)se_c * 64 + l * 2);
            sa += w_c;
            a0 = fmaf(bflo(p.x), w_c, a0);
            a1 = fmaf(bfhi(p.x), w_c, a1);
            a2 = fmaf(bflo(p.y), w_c, a2);
            a3 = fmaf(bfhi(p.y), w_c, a3);
        }
    }
    // merge halves
    a0 += __shfl_xor(a0, 32); a1 += __shfl_xor(a1, 32);
    a2 += __shfl_xor(a2, 32); a3 += __shfl_xor(a3, 32);
    sa += __shfl_xor(sa, 32);
    float inv = (d > 0) ? 1.f / sa : 0.f;

    float4 b4 = ((const float4*)bias)[l];
    float r0 = a0 * inv + b4.x, r1 = a1 * inv + b4.y;
    float r2 = a2 * inv + b4.z, r3 = a3 * inv + b4.w;

    if (!final_layer) {
        if (half == 0) {
            r0 = fmaxf(r0, 0.f); r1 = fmaxf(r1, 0.f);
            r2 = fmaxf(r2, 0.f); r3 = fmaxf(r3, 0.f);
            ((uint2*)out)[(size_t)n * 32 + l] = make_uint2(bfpack(r0, r1), bfpack(r2, r3));
        }
    } else {
        // mean over heads: lanes l, l^8, l^16, l^24 hold the 4 heads at same offset
        r0 += __shfl_xor(r0, 8); r0 += __shfl_xor(r0, 16);
        r1 += __shfl_xor(r1, 8); r1 += __shfl_xor(r1, 16);
        r2 += __shfl_xor(r2, 8); r2 += __shfl_xor(r2, 16);
        r3 += __shfl_xor(r3, 8); r3 += __shfl_xor(r3, 16);
        if (half == 0 && l < 8)
            ((float4*)out)[(size_t)n * 8 + l] =
                make_float4(0.25f * r0, 0.25f * r1, 0.25f * r2, 0.25f * r3);
    }
}

extern "C" void kernel_launch(void* const* d_in, const int* in_sizes, int n_in,
                              void* d_out, int out_size, void* d_ws, size_t ws_size,
                              hipStream_t stream) {
    const float* feat = (const float*)d_in[0];
    const int* src = (const int*)d_in[1];
    const int* dst = (const int*)d_in[2];
    const float* W1 = (const float*)d_in[3];
    const float* al1 = (const float*)d_in[4];
    const float* ar1 = (const float*)d_in[5];
    const float* b1 = (const float*)d_in[6];
    const float* W2 = (const float*)d_in[7];
    const float* al2 = (const float*)d_in[8];
    const float* ar2 = (const float*)d_in[9];
    const float* b2 = (const float*)d_in[10];
    float* out = (float*)d_out;

    char* ws = (char*)d_ws;
    size_t off = 0;
    auto alloc = [&](size_t bytes) {
        void* p = ws + off;
        off += (bytes + 255) & ~(size_t)255;
        return p;
    };
    int* deg = (int*)alloc((size_t)N_NODES * 4);
    int* rs = (int*)alloc((size_t)N_NODES * 4);
    int* cursor = (int*)alloc((size_t)N_NODES * 4);
    int* bsums = (int*)alloc(128 * 4);
    int* csr_src = (int*)alloc((size_t)N_EDGES * 4);
    int* csr_dst = (int*)alloc((size_t)N_EDGES * 4);
    unsigned* Hb = (unsigned*)alloc((size_t)N_NODES * 64 * 4);     // bf16 H pairs
    float* el = (float*)alloc((size_t)N_NODES * 4 * 4);
    float* er = (float*)alloc((size_t)N_NODES * 4 * 4);
    float* alpha = (float*)alloc((size_t)N_EDGES * 4 * 4);
    unsigned* out1b = (unsigned*)alloc((size_t)N_NODES * 64 * 4);  // bf16 relu(out1)
    unsigned short* wt1 = (unsigned short*)alloc(128 * 128 * 2);
    unsigned short* wt2 = (unsigned short*)alloc(128 * 128 * 2);

    hipMemsetAsync(deg, 0, (size_t)N_NODES * 4, stream);

    k_hist<<<(N_EDGES + 255) / 256, 256, 0, stream>>>(dst, deg);
    k_scan1<<<98, 256, 0, stream>>>(deg, rs, bsums);
    k_scan2<<<1, 256, 0, stream>>>(bsums, 98);
    k_scan3<<<(N_NODES + 255) / 256, 256, 0, stream>>>(rs, bsums, cursor);
    k_scatter<<<(N_EDGES + 255) / 256, 256, 0, stream>>>(src, dst, cursor, csr_src, csr_dst);
    k_wprep2<<<128, 256, 0, stream>>>(W1, W2, wt1, wt2);

    int gemm_blocks = (N_NODES + 127) / 128;
    int alpha_blocks = (N_EDGES + 255) / 256;
    int gat_blocks = (N_NODES + 3) / 4;

    // layer 1
    k_gemm<<<gemm_blocks, 256, 0, stream>>>(feat, wt1, al1, ar1, Hb, el, er, 0);
    k_alpha<<<alpha_blocks, 256, 0, stream>>>(csr_src, csr_dst, el, er, alpha);
    k_gather<<<gat_blocks, 256, 0, stream>>>(rs, deg, csr_src, alpha, Hb, b1, out1b, 0);
    // layer 2
    k_gemm<<<gemm_blocks, 256, 0, stream>>>(out1b, wt2, al2, ar2, Hb, el, er, 1);
    k_alpha<<<alpha_blocks, 256, 0, stream>>>(csr_src, csr_dst, el, er, alpha);
    k_gather<<<gat_blocks, 256, 0, stream>>>(rs, deg, csr_src, alpha, Hb, b2, out, 1);
}

// Round 5
// 338.592 us; speedup vs baseline: 1.1106x; 1.1106x over previous
//
#include <hip/hip_runtime.h>
#include <math.h>

#define N_NODES 100000
#define N_EDGES 800000
#define NEG_SLOPE 0.2f

typedef __attribute__((ext_vector_type(8))) short short8;
typedef __attribute__((ext_vector_type(4))) float floatx4;

__device__ __forceinline__ float lrelu(float x) { return x > 0.f ? x : NEG_SLOPE * x; }

__device__ __forceinline__ unsigned bf16_rne(float f) {
    unsigned u = __float_as_uint(f);
    return (u + 0x7fffu + ((u >> 16) & 1u)) >> 16;
}
__device__ __forceinline__ unsigned bfpack(float lo, float hi) {
    return bf16_rne(lo) | (bf16_rne(hi) << 16);
}
__device__ __forceinline__ float bflo(unsigned p) { return __uint_as_float(p << 16); }
__device__ __forceinline__ float bfhi(unsigned p) { return __uint_as_float(p & 0xffff0000u); }

// ---------------- CSR build ----------------
__global__ void k_hist(const int* __restrict__ dst, int* __restrict__ deg) {
    int e = blockIdx.x * blockDim.x + threadIdx.x;
    if (e < N_EDGES) atomicAdd(&deg[dst[e]], 1);
}

__global__ __launch_bounds__(256) void k_scan1(const int* __restrict__ deg,
                                               int* __restrict__ rs,
                                               int* __restrict__ bsums) {
    __shared__ int sd[256];
    int tid = threadIdx.x;
    int base = blockIdx.x * 1024 + tid * 4;
    int v0 = (base + 0 < N_NODES) ? deg[base + 0] : 0;
    int v1 = (base + 1 < N_NODES) ? deg[base + 1] : 0;
    int v2 = (base + 2 < N_NODES) ? deg[base + 2] : 0;
    int v3 = (base + 3 < N_NODES) ? deg[base + 3] : 0;
    int t = v0 + v1 + v2 + v3;
    sd[tid] = t;
    __syncthreads();
    int incl = t;
    for (int off = 1; off < 256; off <<= 1) {
        int x = (tid >= off) ? sd[tid - off] : 0;
        __syncthreads();
        incl += x;
        sd[tid] = incl;
        __syncthreads();
    }
    int excl = incl - t;
    if (base + 0 < N_NODES) rs[base + 0] = excl;
    if (base + 1 < N_NODES) rs[base + 1] = excl + v0;
    if (base + 2 < N_NODES) rs[base + 2] = excl + v0 + v1;
    if (base + 3 < N_NODES) rs[base + 3] = excl + v0 + v1 + v2;
    if (tid == 255) bsums[blockIdx.x] = incl;
}

__global__ __launch_bounds__(256) void k_scan2(int* __restrict__ bs, int nb) {
    __shared__ int sd[256];
    int tid = threadIdx.x;
    int t = (tid < nb) ? bs[tid] : 0;
    sd[tid] = t;
    __syncthreads();
    int incl = t;
    for (int off = 1; off < 256; off <<= 1) {
        int x = (tid >= off) ? sd[tid - off] : 0;
        __syncthreads();
        incl += x;
        sd[tid] = incl;
        __syncthreads();
    }
    if (tid < nb) bs[tid] = incl - t;
}

__global__ void k_scan3(int* __restrict__ rs, const int* __restrict__ bs,
                        int* __restrict__ cursor) {
    int idx = blockIdx.x * blockDim.x + threadIdx.x;
    if (idx < N_NODES) {
        int v = rs[idx] + bs[idx >> 10];
        rs[idx] = v;
        cursor[idx] = v;
    }
    if (idx == 0) rs[N_NODES] = N_EDGES;   // sentinel so deg = rs[n+1]-rs[n] everywhere
}

__global__ void k_scatter(const int* __restrict__ src, const int* __restrict__ dst,
                          int* __restrict__ cursor, int* __restrict__ csr_src) {
    int e = blockIdx.x * blockDim.x + threadIdx.x;
    if (e < N_EDGES) {
        int d = dst[e];
        int p = atomicAdd(&cursor[d], 1);
        csr_src[p] = src[e];
    }
}

// ---------------- W transpose + bf16 convert for both layers ----------------
__global__ __launch_bounds__(256) void k_wprep2(const float* __restrict__ W1,
                                                const float* __restrict__ W2,
                                                unsigned short* __restrict__ wt1,
                                                unsigned short* __restrict__ wt2) {
    int tid = blockIdx.x * 256 + threadIdx.x;   // 0..32767
    const float* W = (tid < 16384) ? W1 : W2;
    unsigned short* wt = (tid < 16384) ? wt1 : wt2;
    int t = tid & 16383;
    int n = t >> 7, k = t & 127;
    wt[t] = (unsigned short)bf16_rne(W[k * 128 + n]);
}

// ---------------- MFMA GEMM: h = X @ W (bf16 in, fp32 acc) + el/er epilogue ----------------
__global__ __launch_bounds__(256) void k_gemm(const void* __restrict__ Xv,
                                              const unsigned short* __restrict__ wt,
                                              const float* __restrict__ al,
                                              const float* __restrict__ ar,
                                              unsigned* __restrict__ Hb,
                                              float* __restrict__ EL,
                                              float* __restrict__ ER,
                                              int src_bf16) {
    __shared__ unsigned short wsh[128 * 128];   // 32 KB, swizzled [n][k] bf16
    int tid = threadIdx.x;
    int w = tid >> 6, lane = tid & 63;
    int q = lane >> 4, nl = lane & 15;
    int base = blockIdx.x * 128;

    const uint4* wt4 = (const uint4*)wt;
    #pragma unroll
    for (int i = 0; i < 8; i++) {
        int idx = tid + i * 256;                // 0..2047 chunks of 8 shorts
        int rn = idx >> 4, c8 = idx & 15;
        int kc = c8 >> 2, qq = c8 & 3;
        int slot = rn * 128 + ((kc ^ ((rn >> 2) & 3)) * 4 + (qq ^ (rn & 3))) * 8;
        *(uint4*)&wsh[slot] = wt4[idx];
    }

    short8 afr[2][4];
    int row0 = base + w * 32 + nl;
    if (!src_bf16) {
        const float4* X4 = (const float4*)Xv;
        #pragma unroll
        for (int rt = 0; rt < 2; rt++) {
            int rr = row0 + rt * 16; if (rr > N_NODES - 1) rr = N_NODES - 1;
            const float4* px = X4 + (size_t)rr * 32 + q * 2;
            #pragma unroll
            for (int kc = 0; kc < 4; kc++) {
                float4 u = px[kc * 8], v = px[kc * 8 + 1];
                short8 f;
                f[0] = (short)bf16_rne(u.x); f[1] = (short)bf16_rne(u.y);
                f[2] = (short)bf16_rne(u.z); f[3] = (short)bf16_rne(u.w);
                f[4] = (short)bf16_rne(v.x); f[5] = (short)bf16_rne(v.y);
                f[6] = (short)bf16_rne(v.z); f[7] = (short)bf16_rne(v.w);
                afr[rt][kc] = f;
            }
        }
    } else {
        const unsigned short* Xb = (const unsigned short*)Xv;
        #pragma unroll
        for (int rt = 0; rt < 2; rt++) {
            int rr = row0 + rt * 16; if (rr > N_NODES - 1) rr = N_NODES - 1;
            #pragma unroll
            for (int kc = 0; kc < 4; kc++)
                afr[rt][kc] = *(const short8*)(Xb + (size_t)rr * 128 + kc * 32 + q * 8);
        }
    }

    floatx4 acc[2][8];
    #pragma unroll
    for (int rt = 0; rt < 2; rt++)
        #pragma unroll
        for (int ct = 0; ct < 8; ct++)
            acc[rt][ct] = (floatx4){0.f, 0.f, 0.f, 0.f};

    __syncthreads();

    int sw_hi = (nl >> 2) & 3, sw_lo = nl & 3;
    #pragma unroll
    for (int ct = 0; ct < 8; ct++) {
        int rbase = (ct * 16 + nl) * 128;
        #pragma unroll
        for (int kc = 0; kc < 4; kc++) {
            short8 b = *(const short8*)&wsh[rbase + ((kc ^ sw_hi) * 4 + (q ^ sw_lo)) * 8];
            acc[0][ct] = __builtin_amdgcn_mfma_f32_16x16x32_bf16(afr[0][kc], b, acc[0][ct], 0, 0, 0);
            acc[1][ct] = __builtin_amdgcn_mfma_f32_16x16x32_bf16(afr[1][kc], b, acc[1][ct], 0, 0, 0);
        }
    }

    float all_[4], alh_[4], arl_[4], arh_[4];
    #pragma unroll
    for (int h = 0; h < 4; h++) {
        all_[h] = al[h * 32 + nl]; alh_[h] = al[h * 32 + 16 + nl];
        arl_[h] = ar[h * 32 + nl]; arh_[h] = ar[h * 32 + 16 + nl];
    }
    #pragma unroll
    for (int rt = 0; rt < 2; rt++) {
        #pragma unroll
        for (int r = 0; r < 4; r++) {
            int row = base + w * 32 + rt * 16 + q * 4 + r;
            bool valid = row < N_NODES;
            unsigned* hrow = Hb + (size_t)row * 64;
            #pragma unroll
            for (int ct = 0; ct < 8; ct++) {
                float vlo = acc[rt][ct][r];
                float vhi = __shfl_down(vlo, 1);
                if (valid && !(nl & 1)) hrow[ct * 8 + (nl >> 1)] = bfpack(vlo, vhi);
            }
            #pragma unroll
            for (int h = 0; h < 4; h++) {
                float pel = acc[rt][2 * h][r] * all_[h] + acc[rt][2 * h + 1][r] * alh_[h];
                float per = acc[rt][2 * h][r] * arl_[h] + acc[rt][2 * h + 1][r] * arh_[h];
                #pragma unroll
                for (int o = 1; o < 16; o <<= 1) {
                    pel += __shfl_xor(pel, o);
                    per += __shfl_xor(per, o);
                }
                if (valid && nl == 0) { EL[row * 4 + h] = pel; ER[row * 4 + h] = per; }
            }
        }
    }
}

// ---------------- gather v3: fused softmax + aggregate ----------------
// One wave handles 4 consecutive nodes. 16 lanes per edge (uint4 = 16B/lane =
// full 256B H row); 4 groups x 2 batches = 8 edges (8 independent H-loads) per
// iteration. alpha computed inline from EL gather (16B, L2-resident) + per-node
// ER broadcast. Denominator free per-lane; group merge via 2 shfl_xor at node end.
__global__ __launch_bounds__(256) void k_gather(const int* __restrict__ rs,
                                                const int* __restrict__ csr_src,
                                                const float* __restrict__ EL,
                                                const float* __restrict__ ER,
                                                const unsigned* __restrict__ Hb,
                                                const float* __restrict__ bias,
                                                void* __restrict__ out,
                                                int final_layer) {
    int wid = (blockIdx.x * blockDim.x + threadIdx.x) >> 6;
    int lane = threadIdx.x & 63;
    int g = lane >> 4, l16 = lane & 15;
    int h = l16 >> 2;
    int n0 = wid * 4;
    if (n0 >= N_NODES) return;
    int nend = min(n0 + 4, N_NODES);

    float bv[8];
    #pragma unroll
    for (int c = 0; c < 8; c++) bv[c] = bias[l16 * 8 + c];

    for (int n = n0; n < nend; n++) {
        int s = rs[n], e = rs[n + 1];
        float erh = ER[n * 4 + h];
        float acc[8];
        #pragma unroll
        for (int c = 0; c < 8; c++) acc[c] = 0.f;
        float sa = 0.f;

        for (int j = s; j < e; j += 8) {
            int j0 = j + g, j1 = j + 4 + g;
            uint4 p0 = make_uint4(0, 0, 0, 0), p1 = make_uint4(0, 0, 0, 0);
            float w0 = 0.f, w1 = 0.f;
            if (j0 < e) {
                int s0 = csr_src[j0];
                p0 = *(const uint4*)(Hb + (size_t)s0 * 64 + l16 * 4);
                w0 = __expf(lrelu(EL[s0 * 4 + h] + erh));
            }
            if (j1 < e) {
                int s1 = csr_src[j1];
                p1 = *(const uint4*)(Hb + (size_t)s1 * 64 + l16 * 4);
                w1 = __expf(lrelu(EL[s1 * 4 + h] + erh));
            }
            sa += w0 + w1;
            acc[0] = fmaf(bflo(p0.x), w0, acc[0]); acc[1] = fmaf(bfhi(p0.x), w0, acc[1]);
            acc[2] = fmaf(bflo(p0.y), w0, acc[2]); acc[3] = fmaf(bfhi(p0.y), w0, acc[3]);
            acc[4] = fmaf(bflo(p0.z), w0, acc[4]); acc[5] = fmaf(bfhi(p0.z), w0, acc[5]);
            acc[6] = fmaf(bflo(p0.w), w0, acc[6]); acc[7] = fmaf(bfhi(p0.w), w0, acc[7]);
            acc[0] = fmaf(bflo(p1.x), w1, acc[0]); acc[1] = fmaf(bfhi(p1.x), w1, acc[1]);
            acc[2] = fmaf(bflo(p1.y), w1, acc[2]); acc[3] = fmaf(bfhi(p1.y), w1, acc[3]);
            acc[4] = fmaf(bflo(p1.z), w1, acc[4]); acc[5] = fmaf(bfhi(p1.z), w1, acc[5]);
            acc[6] = fmaf(bflo(p1.w), w1, acc[6]); acc[7] = fmaf(bfhi(p1.w), w1, acc[7]);
        }

        // merge the 4 edge-groups
        #pragma unroll
        for (int c = 0; c < 8; c++) {
            acc[c] += __shfl_xor(acc[c], 16);
            acc[c] += __shfl_xor(acc[c], 32);
        }
        sa += __shfl_xor(sa, 16);
        sa += __shfl_xor(sa, 32);
        float inv = (e > s) ? 1.f / sa : 0.f;

        float r[8];
        #pragma unroll
        for (int c = 0; c < 8; c++) r[c] = acc[c] * inv + bv[c];

        if (!final_layer) {
            if (g == 0) {
                uint4 pk;
                pk.x = bfpack(fmaxf(r[0], 0.f), fmaxf(r[1], 0.f));
                pk.y = bfpack(fmaxf(r[2], 0.f), fmaxf(r[3], 0.f));
                pk.z = bfpack(fmaxf(r[4], 0.f), fmaxf(r[5], 0.f));
                pk.w = bfpack(fmaxf(r[6], 0.f), fmaxf(r[7], 0.f));
                *(uint4*)((unsigned*)out + (size_t)n * 64 + l16 * 4) = pk;
            }
        } else {
            // mean over heads: sum lanes l16, l16^4, l16^8 (head index = l16>>2)
            #pragma unroll
            for (int c = 0; c < 8; c++) {
                r[c] += __shfl_xor(r[c], 4);
                r[c] += __shfl_xor(r[c], 8);
            }
            if (g == 0 && l16 < 4) {
                float* po = (float*)out + (size_t)n * 32 + l16 * 8;
                *(float4*)po = make_float4(0.25f * r[0], 0.25f * r[1], 0.25f * r[2], 0.25f * r[3]);
                *(float4*)(po + 4) = make_float4(0.25f * r[4], 0.25f * r[5], 0.25f * r[6], 0.25f * r[7]);
            }
        }
    }
}

extern "C" void kernel_launch(void* const* d_in, const int* in_sizes, int n_in,
                              void* d_out, int out_size, void* d_ws, size_t ws_size,
                              hipStream_t stream) {
    const float* feat = (const float*)d_in[0];
    const int* src = (const int*)d_in[1];
    const int* dst = (const int*)d_in[2];
    const float* W1 = (const float*)d_in[3];
    const float* al1 = (const float*)d_in[4];
    const float* ar1 = (const float*)d_in[5];
    const float* b1 = (const float*)d_in[6];
    const float* W2 = (const float*)d_in[7];
    const float* al2 = (const float*)d_in[8];
    const float* ar2 = (const float*)d_in[9];
    const float* b2 = (const float*)d_in[10];
    float* out = (float*)d_out;

    char* ws = (char*)d_ws;
    size_t off = 0;
    auto alloc = [&](size_t bytes) {
        void* p = ws + off;
        off += (bytes + 255) & ~(size_t)255;
        return p;
    };
    int* deg = (int*)alloc((size_t)N_NODES * 4);
    int* rs = (int*)alloc(((size_t)N_NODES + 1) * 4);   // +1 sentinel
    int* cursor = (int*)alloc((size_t)N_NODES * 4);
    int* bsums = (int*)alloc(128 * 4);
    int* csr_src = (int*)alloc((size_t)N_EDGES * 4);
    unsigned* Hb = (unsigned*)alloc((size_t)N_NODES * 64 * 4);     // bf16 H pairs
    float* el = (float*)alloc((size_t)N_NODES * 4 * 4);
    float* er = (float*)alloc((size_t)N_NODES * 4 * 4);
    unsigned* out1b = (unsigned*)alloc((size_t)N_NODES * 64 * 4);  // bf16 relu(out1)
    unsigned short* wt1 = (unsigned short*)alloc(128 * 128 * 2);
    unsigned short* wt2 = (unsigned short*)alloc(128 * 128 * 2);

    hipMemsetAsync(deg, 0, (size_t)N_NODES * 4, stream);

    k_hist<<<(N_EDGES + 255) / 256, 256, 0, stream>>>(dst, deg);
    k_scan1<<<98, 256, 0, stream>>>(deg, rs, bsums);
    k_scan2<<<1, 256, 0, stream>>>(bsums, 98);
    k_scan3<<<(N_NODES + 255) / 256, 256, 0, stream>>>(rs, bsums, cursor);
    k_scatter<<<(N_EDGES + 255) / 256, 256, 0, stream>>>(src, dst, cursor, csr_src);
    k_wprep2<<<128, 256, 0, stream>>>(W1, W2, wt1, wt2);

    int gemm_blocks = (N_NODES + 127) / 128;
    int gat_blocks = (N_NODES + 15) / 16;   // 4 waves/block, 4 nodes/wave

    // layer 1
    k_gemm<<<gemm_blocks, 256, 0, stream>>>(feat, wt1, al1, ar1, Hb, el, er, 0);
    k_gather<<<gat_blocks, 256, 0, stream>>>(rs, csr_src, el, er, Hb, b1, out1b, 0);
    // layer 2
    k_gemm<<<gemm_blocks, 256, 0, stream>>>(out1b, wt2, al2, ar2, Hb, el, er, 1);
    k_gather<<<gat_blocks, 256, 0, stream>>>(rs, csr_src, el, er, Hb, b2, out, 1);
}